// Round 2
// baseline (1463.512 us; speedup 1.0000x reference)
//
#include <hip/hip_runtime.h>

using u16 = unsigned short;
using bf16x8 = __attribute__((ext_vector_type(8))) short;
using f32x4 = __attribute__((ext_vector_type(4))) float;

__device__ __forceinline__ u16 f2bf(float f) {
  unsigned x = __float_as_uint(f);
  x += 0x7fffu + ((x >> 16) & 1u);
  return (u16)(x >> 16);
}

// ---------------- fp32 -> bf16 conversion ----------------
__global__ __launch_bounds__(256) void cvt_kernel(const float* __restrict__ src,
                                                  u16* __restrict__ dst, int n) {
  int i = blockIdx.x * 256 + threadIdx.x;
  if (i < n) dst[i] = f2bf(src[i]);
}

// ---------------- generic bf16 GEMM: C = A@B + bias ----------------
// A [M,K] row-major bf16, B [K,N] row-major bf16 (+ per-z offset), bias fp32.
// out_mode: 0 = fp32 row-major, 1 = bf16 row-major, 2 = bf16 transposed per
// batch for V: C[b][col][t] with row = b*1024 + t  (layout [b][512][1024]).
__global__ __launch_bounds__(256) void gemm_kernel(
    const u16* __restrict__ A, const u16* __restrict__ B,
    const float* __restrict__ bias, void* __restrict__ Cout,
    int M, int N, int K, long long sBz, long long sbz, long long sCzBytes,
    int out_mode)
{
  __shared__ __align__(16) u16 As[128][40];
  __shared__ __align__(16) u16 Bs[128][40];
  const f32x4 zero4 = {0.f, 0.f, 0.f, 0.f};

  const u16* Bp = B + (size_t)blockIdx.z * sBz;
  const float* biasp = bias + (size_t)blockIdx.z * sbz;
  char* Cp = (char*)Cout + (size_t)blockIdx.z * sCzBytes;

  int tid = threadIdx.x;
  int lane = tid & 63, wave = tid >> 6;
  int m = lane & 15, quad = lane >> 4;
  int wm = (wave >> 1) * 64, wn = (wave & 1) * 64;
  int m0 = blockIdx.y * 128, n0 = blockIdx.x * 128;

  f32x4 acc[4][4];
  #pragma unroll
  for (int i = 0; i < 4; i++)
    #pragma unroll
    for (int j = 0; j < 4; j++) acc[i][j] = zero4;

  for (int k0 = 0; k0 < K; k0 += 32) {
    // stage A tile 128x32 (row-major, padded rows of 40)
    #pragma unroll
    for (int i = 0; i < 2; i++) {
      int g = tid + 256 * i;
      int r = g >> 2, c = (g & 3) << 3;
      *(float4*)&As[r][c] = *(const float4*)(A + (size_t)(m0 + r) * K + k0 + c);
      // stage B tile 32x128, transposed into Bs[n][k]
      int r2 = g >> 4, c2 = (g & 15) << 3;
      union { float4 f; u16 u[8]; } cv;
      cv.f = *(const float4*)(Bp + (size_t)(k0 + r2) * N + n0 + c2);
      #pragma unroll
      for (int j = 0; j < 8; j++) Bs[c2 + j][r2] = cv.u[j];
    }
    __syncthreads();

    bf16x8 af[4], bfr[4];
    #pragma unroll
    for (int t = 0; t < 4; t++) {
      af[t]  = *(const bf16x8*)&As[wm + t * 16 + m][quad * 8];
      bfr[t] = *(const bf16x8*)&Bs[wn + t * 16 + m][quad * 8];
    }
    #pragma unroll
    for (int mt = 0; mt < 4; mt++)
      #pragma unroll
      for (int nt = 0; nt < 4; nt++)
        acc[mt][nt] = __builtin_amdgcn_mfma_f32_16x16x32_bf16(af[mt], bfr[nt],
                                                              acc[mt][nt], 0, 0, 0);
    __syncthreads();
  }

  // epilogue: C/D layout col = lane&15, row = quad*4 + reg
  #pragma unroll
  for (int nt = 0; nt < 4; nt++) {
    int col = n0 + wn + nt * 16 + m;
    float bb = biasp[col];
    #pragma unroll
    for (int mt = 0; mt < 4; mt++) {
      #pragma unroll
      for (int r = 0; r < 4; r++) {
        int row = m0 + wm + mt * 16 + quad * 4 + r;
        float v = acc[mt][nt][r] + bb;
        if (out_mode == 1) {
          ((u16*)Cp)[(size_t)row * N + col] = f2bf(v);
        } else if (out_mode == 2) {
          int bb2 = row >> 10, tt2 = row & 1023;
          ((u16*)Cp)[((size_t)bb2 * 512 + col) * 1024 + tt2] = f2bf(v);
        } else {
          ((float*)Cp)[(size_t)row * N + col] = v;
        }
      }
    }
  }
}

// ---------------- flash attention ----------------
// Q,K: [G][B][T=1024][D=512] bf16 (group-local head index z = blockIdx.z).
// V: [G][B][D=512][T=1024] bf16 (pre-transposed).
// Out: concat layout [B][T][H=8][D] bf16, global head h = h0 + z.
// Block: 512 threads = 8 waves; wave w owns q-rows qb*128 + w*16 .. +15.
__global__ __launch_bounds__(512) void attn_kernel(
    const u16* __restrict__ Qg, const u16* __restrict__ Kg,
    const u16* __restrict__ Vg, u16* __restrict__ Oc, int h0)
{
  __shared__ __align__(16) u16 Kt[32][520];    // [key][d] tile
  __shared__ __align__(16) u16 Vt[256][40];    // [d-half][key] tile
  __shared__ __align__(16) u16 Pl[8][16][40];  // per-wave P round-trip
  const f32x4 zero4 = {0.f, 0.f, 0.f, 0.f};

  int qb = blockIdx.x, b = blockIdx.y, z = blockIdx.z;
  int h = h0 + z;
  size_t hb = ((size_t)z * 8 + b) * (size_t)(1024 * 512);
  const u16* Qp = Qg + hb;
  const u16* Kp = Kg + hb;
  const u16* Vp = Vg + hb;

  int tid = threadIdx.x, lane = tid & 63, wave = tid >> 6;
  int m = lane & 15, quad = lane >> 4;
  int q0 = qb * 128 + wave * 16;

  // Q fragments for this wave's 16 rows, K-dim = 512 in 16 chunks of 32
  bf16x8 aq[16];
  #pragma unroll
  for (int kc = 0; kc < 16; kc++)
    aq[kc] = *(const bf16x8*)(Qp + (size_t)(q0 + m) * 512 + kc * 32 + quad * 8);

  f32x4 acc[32];
  #pragma unroll
  for (int dt = 0; dt < 32; dt++) acc[dt] = zero4;
  float mrow[4] = {-1e30f, -1e30f, -1e30f, -1e30f};
  float lrow[4] = {0.f, 0.f, 0.f, 0.f};
  const float scale = 0.04419417382415922f;  // 1/sqrt(512)

  for (int kt = 0; kt < 32; kt++) {
    int kr0 = kt * 32;
    // stage K tile [32 keys][512 d]
    #pragma unroll
    for (int i = 0; i < 4; i++) {
      int gg = tid + 512 * i;
      int r = gg >> 6, c = (gg & 63) << 3;
      *(float4*)&Kt[r][c] = *(const float4*)(Kp + (size_t)(kr0 + r) * 512 + c);
    }
    // stage V half 0: Vt[d][key], d = 0..255
    #pragma unroll
    for (int i = 0; i < 2; i++) {
      int gg = tid + 512 * i;
      int d = gg >> 2, ck = (gg & 3) << 3;
      *(float4*)&Vt[d][ck] = *(const float4*)(Vp + (size_t)d * 1024 + kr0 + ck);
    }
    __syncthreads();

    // S = Q K^T for this wave's 16 rows x 32 keys
    f32x4 s0 = zero4, s1 = zero4;
    #pragma unroll
    for (int kc = 0; kc < 16; kc++) {
      bf16x8 bk0 = *(const bf16x8*)&Kt[m][kc * 32 + quad * 8];
      bf16x8 bk1 = *(const bf16x8*)&Kt[m + 16][kc * 32 + quad * 8];
      s0 = __builtin_amdgcn_mfma_f32_16x16x32_bf16(aq[kc], bk0, s0, 0, 0, 0);
      s1 = __builtin_amdgcn_mfma_f32_16x16x32_bf16(aq[kc], bk1, s1, 0, 0, 0);
    }

    // online softmax, all in-register (rows = quad*4+r, cols across 16 lanes)
    float al[4];
    #pragma unroll
    for (int r = 0; r < 4; r++) {
      float x0 = s0[r] * scale, x1 = s1[r] * scale;
      float mx = fmaxf(x0, x1);
      #pragma unroll
      for (int off = 1; off < 16; off <<= 1) mx = fmaxf(mx, __shfl_xor(mx, off));
      float mnew = fmaxf(mrow[r], mx);
      float alpha = __expf(mrow[r] - mnew);
      float p0 = __expf(x0 - mnew), p1 = __expf(x1 - mnew);
      float ps = p0 + p1;
      #pragma unroll
      for (int off = 1; off < 16; off <<= 1) ps += __shfl_xor(ps, off);
      lrow[r] = lrow[r] * alpha + ps;
      mrow[r] = mnew;
      al[r] = alpha;
      // C-layout -> LDS (row-major P [16 rows][32 keys], padded to 40)
      Pl[wave][quad * 4 + r][m] = f2bf(p0);
      Pl[wave][quad * 4 + r][m + 16] = f2bf(p1);
    }
    asm volatile("s_waitcnt lgkmcnt(0)" ::: "memory");
    bf16x8 ap = *(const bf16x8*)&Pl[wave][m][quad * 8];  // A-layout fragment

    // PV, d-half 0
    #pragma unroll
    for (int dt = 0; dt < 16; dt++) {
      f32x4 t4 = acc[dt];
      #pragma unroll
      for (int r = 0; r < 4; r++) t4[r] *= al[r];
      bf16x8 bv = *(const bf16x8*)&Vt[dt * 16 + m][quad * 8];
      acc[dt] = __builtin_amdgcn_mfma_f32_16x16x32_bf16(ap, bv, t4, 0, 0, 0);
    }
    __syncthreads();
    // stage V half 1: d = 256..511
    #pragma unroll
    for (int i = 0; i < 2; i++) {
      int gg = tid + 512 * i;
      int d = gg >> 2, ck = (gg & 3) << 3;
      *(float4*)&Vt[d][ck] = *(const float4*)(Vp + (size_t)(256 + d) * 1024 + kr0 + ck);
    }
    __syncthreads();
    // PV, d-half 1
    #pragma unroll
    for (int dt = 0; dt < 16; dt++) {
      f32x4 t4 = acc[16 + dt];
      #pragma unroll
      for (int r = 0; r < 4; r++) t4[r] *= al[r];
      bf16x8 bv = *(const bf16x8*)&Vt[dt * 16 + m][quad * 8];
      acc[16 + dt] = __builtin_amdgcn_mfma_f32_16x16x32_bf16(ap, bv, t4, 0, 0, 0);
    }
    __syncthreads();
  }

  float linv[4];
  #pragma unroll
  for (int r = 0; r < 4; r++) linv[r] = 1.f / lrow[r];
  #pragma unroll
  for (int dt = 0; dt < 32; dt++) {
    #pragma unroll
    for (int r = 0; r < 4; r++) {
      size_t trow = (size_t)b * 1024 + q0 + quad * 4 + r;
      Oc[(trow * 8 + h) * 512 + dt * 16 + m] = f2bf(acc[dt][r] * linv[r]);
    }
  }
}

// ---------------- fused residual + LayerNorm ----------------
// out = LN( (do_relu ? relu(xin) : xin) + res ) * g + b;  row = 512 elems.
__global__ __launch_bounds__(256) void ln_kernel(
    const float* __restrict__ xin, const float* __restrict__ res,
    const float* __restrict__ gam, const float* __restrict__ bet,
    float* __restrict__ outf, u16* __restrict__ outb, int do_relu)
{
  __shared__ float red[4];
  __shared__ float red2[4];
  int row = blockIdx.x, t = threadIdx.x;
  size_t base = (size_t)row * 512;
  float a0 = xin[base + t], a1 = xin[base + 256 + t];
  if (do_relu) { a0 = fmaxf(a0, 0.f); a1 = fmaxf(a1, 0.f); }
  a0 += res[base + t]; a1 += res[base + 256 + t];

  float s = a0 + a1;
  #pragma unroll
  for (int off = 32; off > 0; off >>= 1) s += __shfl_xor(s, off);
  if ((t & 63) == 0) red[t >> 6] = s;
  __syncthreads();
  float mu = (red[0] + red[1] + red[2] + red[3]) * (1.f / 512.f);

  float d0 = a0 - mu, d1 = a1 - mu;
  float q = d0 * d0 + d1 * d1;
  #pragma unroll
  for (int off = 32; off > 0; off >>= 1) q += __shfl_xor(q, off);
  if ((t & 63) == 0) red2[t >> 6] = q;
  __syncthreads();
  float var = (red2[0] + red2[1] + red2[2] + red2[3]) * (1.f / 512.f);
  float rs = rsqrtf(var + 1e-5f);

  float o0 = d0 * rs * gam[t] + bet[t];
  float o1 = d1 * rs * gam[t + 256] + bet[t + 256];
  outf[base + t] = o0;
  outf[base + 256 + t] = o1;
  if (outb) { outb[base + t] = f2bf(o0); outb[base + 256 + t] = f2bf(o1); }
}

// ---------------- host launch ----------------
extern "C" void kernel_launch(void* const* d_in, const int* in_sizes, int n_in,
                              void* d_out, int out_size, void* d_ws, size_t ws_size,
                              hipStream_t stream) {
  const float* x   = (const float*)d_in[0];
  const float* Wq  = (const float*)d_in[1];
  const float* bq  = (const float*)d_in[2];
  const float* Wk  = (const float*)d_in[3];
  const float* bk  = (const float*)d_in[4];
  const float* Wv  = (const float*)d_in[5];
  const float* bv  = (const float*)d_in[6];
  const float* Wo  = (const float*)d_in[7];
  const float* bo  = (const float*)d_in[8];
  const float* g1  = (const float*)d_in[9];
  const float* bn1 = (const float*)d_in[10];
  const float* W1  = (const float*)d_in[11];
  const float* bf1 = (const float*)d_in[12];
  const float* W2  = (const float*)d_in[13];
  const float* bf2 = (const float*)d_in[14];
  const float* g2  = (const float*)d_in[15];
  const float* bn2 = (const float*)d_in[16];

  // Head-group size chosen deterministically from ws_size (graph-safe:
  // identical work every call). Peak bytes = 113,246,208 + 25,165,824*G.
  const size_t HB = 8388608;  // bytes per head per tensor (bf16 1024*512*8batch)
  size_t G = 1;
  if (ws_size >= 113246208ULL + 25165824ULL * 8) G = 8;
  else if (ws_size >= 113246208ULL + 25165824ULL * 4) G = 4;
  else if (ws_size >= 113246208ULL + 25165824ULL * 2) G = 2;

  char* ws = (char*)d_ws;
  u16* xb  = (u16*)(ws + 0);            //  8,388,608
  u16* WqB = (u16*)(ws + 8388608);      //  4,194,304 each
  u16* WkB = (u16*)(ws + 12582912);
  u16* WvB = (u16*)(ws + 16777216);
  u16* WoB = (u16*)(ws + 20971520);
  u16* W1B = (u16*)(ws + 25165824);     //  2,097,152 each
  u16* W2B = (u16*)(ws + 27262976);
  u16* cc  = (u16*)(ws + 29360128);     // 67,108,864  [B][T][H*D]
  u16* Qg  = (u16*)(ws + 96468992);     // G * 8,388,608
  u16* Kg  = (u16*)(ws + 96468992 + G * HB);
  u16* Vg  = (u16*)(ws + 96468992 + 2 * G * HB);
  float* mha = (float*)(ws + 96468992 + 3 * G * HB);  // 16,777,216
  // aliases of dead regions (valid after attention / Wo GEMM):
  float* y1f = (float*)(ws + 96468992);   // over Qg (dead after attn)
  u16*   y1b = (u16*)(ws + 113246208);    // over Kg/Vg tail (dead after attn)
  u16*   ff1 = (u16*)(ws + 29360128);     // over cc (dead after Wo GEMM)
  float* ff2 = (float*)(ws + 62914560);   // over cc tail

  // 1) casts to bf16
  cvt_kernel<<<16384, 256, 0, stream>>>(x,  xb,  4194304);
  cvt_kernel<<<8192,  256, 0, stream>>>(Wq, WqB, 2097152);
  cvt_kernel<<<8192,  256, 0, stream>>>(Wk, WkB, 2097152);
  cvt_kernel<<<8192,  256, 0, stream>>>(Wv, WvB, 2097152);
  cvt_kernel<<<8192,  256, 0, stream>>>(Wo, WoB, 2097152);
  cvt_kernel<<<4096,  256, 0, stream>>>(W1, W1B, 1048576);
  cvt_kernel<<<4096,  256, 0, stream>>>(W2, W2B, 1048576);

  // 2) per head-group: QKV projections + flash attention -> cc
  dim3 blk(256);
  for (int h0 = 0; h0 < 8; h0 += (int)G) {
    dim3 gqkv(4, 64, (unsigned)G);
    gemm_kernel<<<gqkv, blk, 0, stream>>>(xb, WqB + (size_t)h0 * 262144,
                                          bq + h0 * 512, Qg, 8192, 512, 512,
                                          262144LL, 512LL, (long long)HB, 1);
    gemm_kernel<<<gqkv, blk, 0, stream>>>(xb, WkB + (size_t)h0 * 262144,
                                          bk + h0 * 512, Kg, 8192, 512, 512,
                                          262144LL, 512LL, (long long)HB, 1);
    gemm_kernel<<<gqkv, blk, 0, stream>>>(xb, WvB + (size_t)h0 * 262144,
                                          bv + h0 * 512, Vg, 8192, 512, 512,
                                          262144LL, 512LL, (long long)HB, 2);
    dim3 gattn(8, 8, (unsigned)G);
    attn_kernel<<<gattn, 512, 0, stream>>>(Qg, Kg, Vg, cc, h0);
  }

  // 3) output projection: mha = concat @ Wo + bo (fp32)
  dim3 gwo(4, 64, 1);
  gemm_kernel<<<gwo, blk, 0, stream>>>(cc, WoB, bo, mha, 8192, 512, 4096,
                                       0LL, 0LL, 0LL, 0);

  // 4) y1 = LN(mha + x)
  ln_kernel<<<8192, 256, 0, stream>>>(mha, x, g1, bn1, y1f, y1b, 0);

  // 5) ff1 = y1 @ W1 + b1 (bf16)
  dim3 gff1(16, 64, 1);
  gemm_kernel<<<gff1, blk, 0, stream>>>(y1b, W1B, bf1, ff1, 8192, 2048, 512,
                                        0LL, 0LL, 0LL, 1);

  // 6) ff2 = ff1 @ W2 + b2 (fp32)
  dim3 gff2(4, 64, 1);
  gemm_kernel<<<gff2, blk, 0, stream>>>(ff1, W2B, bf2, ff2, 8192, 512, 2048,
                                        0LL, 0LL, 0LL, 0);

  // 7) out = LN(relu(ff2) + y1)
  ln_kernel<<<8192, 256, 0, stream>>>(ff2, y1f, g2, bn2, (float*)d_out, nullptr, 1);
}

// Round 3
// 950.272 us; speedup vs baseline: 1.5401x; 1.5401x over previous
//
#include <hip/hip_runtime.h>

using u16 = unsigned short;
using bf16x8 = __attribute__((ext_vector_type(8))) short;
using f32x4 = __attribute__((ext_vector_type(4))) float;

__device__ __forceinline__ u16 f2bf(float f) {
  unsigned x = __float_as_uint(f);
  x += 0x7fffu + ((x >> 16) & 1u);
  return (u16)(x >> 16);
}

// ---------------- fp32 -> bf16 conversion ----------------
__global__ __launch_bounds__(256) void cvt_kernel(const float* __restrict__ src,
                                                  u16* __restrict__ dst, int n) {
  int i = blockIdx.x * 256 + threadIdx.x;
  if (i < n) dst[i] = f2bf(src[i]);
}

// ---------------- fp32 [z][K][N] -> bf16 transposed [z][N][K] ----------------
// 32x32 tile via LDS. grid = (N/32, K/32, z), 256 threads.
__global__ __launch_bounds__(256) void cvt_t_kernel(
    const float* __restrict__ src, u16* __restrict__ dst, int K, int N) {
  __shared__ float T[32][33];
  int n0 = blockIdx.x * 32, k0 = blockIdx.y * 32;
  const float* s = src + (size_t)blockIdx.z * K * N;
  u16* d = dst + (size_t)blockIdx.z * K * N;
  int tid = threadIdx.x;
  int r = tid >> 3, c4 = (tid & 7) << 2;  // r=0..31, c4=0..28 step 4
  float4 v = *(const float4*)(s + (size_t)(k0 + r) * N + n0 + c4);
  T[r][c4 + 0] = v.x; T[r][c4 + 1] = v.y; T[r][c4 + 2] = v.z; T[r][c4 + 3] = v.w;
  __syncthreads();
  ushort4 o;
  o.x = f2bf(T[c4 + 0][r]); o.y = f2bf(T[c4 + 1][r]);
  o.z = f2bf(T[c4 + 2][r]); o.w = f2bf(T[c4 + 3][r]);
  *(ushort4*)(d + (size_t)(n0 + r) * K + k0 + c4) = o;
}

// ---------------- bf16 GEMM with pre-transposed B ----------------
// A [M,K] row-major bf16, Bt [N,K] row-major bf16 (+ per-z offset), bias fp32.
// Tile BM x 128, BK=32. 256 threads = 4 waves in 2x2; wave tile (BM/2) x 64.
// out_mode: 0 = fp32 row-major, 1 = bf16 row-major, 2 = bf16 V-transpose
// per batch: C[b][col][t], row = b*1024 + t (layout [b][512][1024]).
template<int BM>
__global__ __launch_bounds__(256) void gemm_bt(
    const u16* __restrict__ A, const u16* __restrict__ Bt,
    const float* __restrict__ bias, void* __restrict__ Cout,
    int M, int N, int K, long long sBz, long long sbz, long long sCzBytes,
    int out_mode)
{
  constexpr int MT = BM / 32;  // m-fragments per wave
  __shared__ __align__(16) u16 As[BM][40];
  __shared__ __align__(16) u16 Bs[128][40];
  const f32x4 zero4 = {0.f, 0.f, 0.f, 0.f};

  const u16* Bp = Bt + (size_t)blockIdx.z * sBz;
  const float* biasp = bias + (size_t)blockIdx.z * sbz;
  char* Cp = (char*)Cout + (size_t)blockIdx.z * sCzBytes;

  int tid = threadIdx.x;
  int lane = tid & 63, wave = tid >> 6;
  int m = lane & 15, quad = lane >> 4;
  int wm = (wave >> 1) * (BM / 2), wn = (wave & 1) * 64;
  int m0 = blockIdx.y * BM, n0 = blockIdx.x * 128;

  f32x4 acc[MT][4];
  #pragma unroll
  for (int i = 0; i < MT; i++)
    #pragma unroll
    for (int j = 0; j < 4; j++) acc[i][j] = zero4;

  for (int k0 = 0; k0 < K; k0 += 32) {
    // stage A tile BM x 32 (16B coalesced, conflict-free)
    #pragma unroll
    for (int i = 0; i < BM / 64; i++) {
      int g = tid + 256 * i;
      int r = g >> 2, c = (g & 3) << 3;
      *(float4*)&As[r][c] = *(const float4*)(A + (size_t)(m0 + r) * K + k0 + c);
    }
    // stage B^T tile 128 x 32 (identical pattern)
    #pragma unroll
    for (int i = 0; i < 2; i++) {
      int g = tid + 256 * i;
      int r = g >> 2, c = (g & 3) << 3;
      *(float4*)&Bs[r][c] = *(const float4*)(Bp + (size_t)(n0 + r) * K + k0 + c);
    }
    __syncthreads();

    bf16x8 af[MT], bfr[4];
    #pragma unroll
    for (int t = 0; t < MT; t++)
      af[t] = *(const bf16x8*)&As[wm + t * 16 + m][quad * 8];
    #pragma unroll
    for (int t = 0; t < 4; t++)
      bfr[t] = *(const bf16x8*)&Bs[wn + t * 16 + m][quad * 8];
    #pragma unroll
    for (int mt = 0; mt < MT; mt++)
      #pragma unroll
      for (int nt = 0; nt < 4; nt++)
        acc[mt][nt] = __builtin_amdgcn_mfma_f32_16x16x32_bf16(af[mt], bfr[nt],
                                                              acc[mt][nt], 0, 0, 0);
    __syncthreads();
  }

  // epilogue: C/D layout col = lane&15, row = quad*4 + reg
  #pragma unroll
  for (int nt = 0; nt < 4; nt++) {
    int col = n0 + wn + nt * 16 + m;
    float bb = biasp[col];
    #pragma unroll
    for (int mt = 0; mt < MT; mt++) {
      #pragma unroll
      for (int r = 0; r < 4; r++) {
        int row = m0 + wm + mt * 16 + quad * 4 + r;
        float v = acc[mt][nt][r] + bb;
        if (out_mode == 1) {
          ((u16*)Cp)[(size_t)row * N + col] = f2bf(v);
        } else if (out_mode == 2) {
          int bb2 = row >> 10, tt2 = row & 1023;
          ((u16*)Cp)[((size_t)bb2 * 512 + col) * 1024 + tt2] = f2bf(v);
        } else {
          ((float*)Cp)[(size_t)row * N + col] = v;
        }
      }
    }
  }
}

// ---------------- flash attention ----------------
// Q,K: [G][B][T=1024][D=512] bf16 (group-local head index z = blockIdx.z).
// V: [G][B][D=512][T=1024] bf16 (pre-transposed).
// Out: concat layout [B][T][H=8][D] bf16, global head h = h0 + z.
// Block: 512 threads = 8 waves; wave w owns q-rows qb*128 + w*16 .. +15.
__global__ __launch_bounds__(512) void attn_kernel(
    const u16* __restrict__ Qg, const u16* __restrict__ Kg,
    const u16* __restrict__ Vg, u16* __restrict__ Oc, int h0)
{
  __shared__ __align__(16) u16 Kt[32][520];    // [key][d] tile
  __shared__ __align__(16) u16 Vt[256][40];    // [d-half][key] tile
  __shared__ __align__(16) u16 Pl[8][16][40];  // per-wave P round-trip
  const f32x4 zero4 = {0.f, 0.f, 0.f, 0.f};

  int qb = blockIdx.x, b = blockIdx.y, z = blockIdx.z;
  int h = h0 + z;
  size_t hb = ((size_t)z * 8 + b) * (size_t)(1024 * 512);
  const u16* Qp = Qg + hb;
  const u16* Kp = Kg + hb;
  const u16* Vp = Vg + hb;

  int tid = threadIdx.x, lane = tid & 63, wave = tid >> 6;
  int m = lane & 15, quad = lane >> 4;
  int q0 = qb * 128 + wave * 16;

  bf16x8 aq[16];
  #pragma unroll
  for (int kc = 0; kc < 16; kc++)
    aq[kc] = *(const bf16x8*)(Qp + (size_t)(q0 + m) * 512 + kc * 32 + quad * 8);

  f32x4 acc[32];
  #pragma unroll
  for (int dt = 0; dt < 32; dt++) acc[dt] = zero4;
  float mrow[4] = {-1e30f, -1e30f, -1e30f, -1e30f};
  float lrow[4] = {0.f, 0.f, 0.f, 0.f};
  const float scale = 0.04419417382415922f;  // 1/sqrt(512)

  for (int kt = 0; kt < 32; kt++) {
    int kr0 = kt * 32;
    #pragma unroll
    for (int i = 0; i < 4; i++) {
      int gg = tid + 512 * i;
      int r = gg >> 6, c = (gg & 63) << 3;
      *(float4*)&Kt[r][c] = *(const float4*)(Kp + (size_t)(kr0 + r) * 512 + c);
    }
    #pragma unroll
    for (int i = 0; i < 2; i++) {
      int gg = tid + 512 * i;
      int d = gg >> 2, ck = (gg & 3) << 3;
      *(float4*)&Vt[d][ck] = *(const float4*)(Vp + (size_t)d * 1024 + kr0 + ck);
    }
    __syncthreads();

    f32x4 s0 = zero4, s1 = zero4;
    #pragma unroll
    for (int kc = 0; kc < 16; kc++) {
      bf16x8 bk0 = *(const bf16x8*)&Kt[m][kc * 32 + quad * 8];
      bf16x8 bk1 = *(const bf16x8*)&Kt[m + 16][kc * 32 + quad * 8];
      s0 = __builtin_amdgcn_mfma_f32_16x16x32_bf16(aq[kc], bk0, s0, 0, 0, 0);
      s1 = __builtin_amdgcn_mfma_f32_16x16x32_bf16(aq[kc], bk1, s1, 0, 0, 0);
    }

    float al[4];
    #pragma unroll
    for (int r = 0; r < 4; r++) {
      float x0 = s0[r] * scale, x1 = s1[r] * scale;
      float mx = fmaxf(x0, x1);
      #pragma unroll
      for (int off = 1; off < 16; off <<= 1) mx = fmaxf(mx, __shfl_xor(mx, off));
      float mnew = fmaxf(mrow[r], mx);
      float alpha = __expf(mrow[r] - mnew);
      float p0 = __expf(x0 - mnew), p1 = __expf(x1 - mnew);
      float ps = p0 + p1;
      #pragma unroll
      for (int off = 1; off < 16; off <<= 1) ps += __shfl_xor(ps, off);
      lrow[r] = lrow[r] * alpha + ps;
      mrow[r] = mnew;
      al[r] = alpha;
      Pl[wave][quad * 4 + r][m] = f2bf(p0);
      Pl[wave][quad * 4 + r][m + 16] = f2bf(p1);
    }
    asm volatile("s_waitcnt lgkmcnt(0)" ::: "memory");
    bf16x8 ap = *(const bf16x8*)&Pl[wave][m][quad * 8];

    #pragma unroll
    for (int dt = 0; dt < 16; dt++) {
      f32x4 t4 = acc[dt];
      #pragma unroll
      for (int r = 0; r < 4; r++) t4[r] *= al[r];
      bf16x8 bv = *(const bf16x8*)&Vt[dt * 16 + m][quad * 8];
      acc[dt] = __builtin_amdgcn_mfma_f32_16x16x32_bf16(ap, bv, t4, 0, 0, 0);
    }
    __syncthreads();
    #pragma unroll
    for (int i = 0; i < 2; i++) {
      int gg = tid + 512 * i;
      int d = gg >> 2, ck = (gg & 3) << 3;
      *(float4*)&Vt[d][ck] = *(const float4*)(Vp + (size_t)(256 + d) * 1024 + kr0 + ck);
    }
    __syncthreads();
    #pragma unroll
    for (int dt = 0; dt < 16; dt++) {
      f32x4 t4 = acc[16 + dt];
      #pragma unroll
      for (int r = 0; r < 4; r++) t4[r] *= al[r];
      bf16x8 bv = *(const bf16x8*)&Vt[dt * 16 + m][quad * 8];
      acc[16 + dt] = __builtin_amdgcn_mfma_f32_16x16x32_bf16(ap, bv, t4, 0, 0, 0);
    }
    __syncthreads();
  }

  float linv[4];
  #pragma unroll
  for (int r = 0; r < 4; r++) linv[r] = 1.f / lrow[r];
  #pragma unroll
  for (int dt = 0; dt < 32; dt++) {
    #pragma unroll
    for (int r = 0; r < 4; r++) {
      size_t trow = (size_t)b * 1024 + q0 + quad * 4 + r;
      Oc[(trow * 8 + h) * 512 + dt * 16 + m] = f2bf(acc[dt][r] * linv[r]);
    }
  }
}

// ---------------- fused residual + LayerNorm ----------------
__global__ __launch_bounds__(256) void ln_kernel(
    const float* __restrict__ xin, const float* __restrict__ res,
    const float* __restrict__ gam, const float* __restrict__ bet,
    float* __restrict__ outf, u16* __restrict__ outb, int do_relu)
{
  __shared__ float red[4];
  __shared__ float red2[4];
  int row = blockIdx.x, t = threadIdx.x;
  size_t base = (size_t)row * 512;
  float a0 = xin[base + t], a1 = xin[base + 256 + t];
  if (do_relu) { a0 = fmaxf(a0, 0.f); a1 = fmaxf(a1, 0.f); }
  a0 += res[base + t]; a1 += res[base + 256 + t];

  float s = a0 + a1;
  #pragma unroll
  for (int off = 32; off > 0; off >>= 1) s += __shfl_xor(s, off);
  if ((t & 63) == 0) red[t >> 6] = s;
  __syncthreads();
  float mu = (red[0] + red[1] + red[2] + red[3]) * (1.f / 512.f);

  float d0 = a0 - mu, d1 = a1 - mu;
  float q = d0 * d0 + d1 * d1;
  #pragma unroll
  for (int off = 32; off > 0; off >>= 1) q += __shfl_xor(q, off);
  if ((t & 63) == 0) red2[t >> 6] = q;
  __syncthreads();
  float var = (red2[0] + red2[1] + red2[2] + red2[3]) * (1.f / 512.f);
  float rs = rsqrtf(var + 1e-5f);

  float o0 = d0 * rs * gam[t] + bet[t];
  float o1 = d1 * rs * gam[t + 256] + bet[t + 256];
  outf[base + t] = o0;
  outf[base + 256 + t] = o1;
  if (outb) { outb[base + t] = f2bf(o0); outb[base + 256 + t] = f2bf(o1); }
}

// ---------------- host launch ----------------
extern "C" void kernel_launch(void* const* d_in, const int* in_sizes, int n_in,
                              void* d_out, int out_size, void* d_ws, size_t ws_size,
                              hipStream_t stream) {
  const float* x   = (const float*)d_in[0];
  const float* Wq  = (const float*)d_in[1];
  const float* bq  = (const float*)d_in[2];
  const float* Wk  = (const float*)d_in[3];
  const float* bk  = (const float*)d_in[4];
  const float* Wv  = (const float*)d_in[5];
  const float* bv  = (const float*)d_in[6];
  const float* Wo  = (const float*)d_in[7];
  const float* bo  = (const float*)d_in[8];
  const float* g1  = (const float*)d_in[9];
  const float* bn1 = (const float*)d_in[10];
  const float* W1  = (const float*)d_in[11];
  const float* bf1 = (const float*)d_in[12];
  const float* W2  = (const float*)d_in[13];
  const float* bf2 = (const float*)d_in[14];
  const float* g2  = (const float*)d_in[15];
  const float* bn2 = (const float*)d_in[16];

  // Head-group size chosen deterministically from ws_size (graph-safe).
  const size_t HB = 8388608;  // bytes per head per tensor
  size_t G = 1;
  if (ws_size >= 113246208ULL + 25165824ULL * 8) G = 8;
  else if (ws_size >= 113246208ULL + 25165824ULL * 4) G = 4;
  else if (ws_size >= 113246208ULL + 25165824ULL * 2) G = 2;

  char* ws = (char*)d_ws;
  u16* xb  = (u16*)(ws + 0);            //  8,388,608
  u16* WqT = (u16*)(ws + 8388608);      //  4,194,304 each (transposed [h][n][k])
  u16* WkT = (u16*)(ws + 12582912);
  u16* WvT = (u16*)(ws + 16777216);
  u16* WoT = (u16*)(ws + 20971520);     //  [512][4096]
  u16* W1T = (u16*)(ws + 25165824);     //  2,097,152  [2048][512]
  u16* W2T = (u16*)(ws + 27262976);     //  [512][2048]
  u16* cc  = (u16*)(ws + 29360128);     // 67,108,864  [B][T][H*D]
  u16* Qg  = (u16*)(ws + 96468992);     // G * 8,388,608
  u16* Kg  = (u16*)(ws + 96468992 + G * HB);
  u16* Vg  = (u16*)(ws + 96468992 + 2 * G * HB);
  float* mha = (float*)(ws + 96468992 + 3 * G * HB);  // 16,777,216
  float* y1f = (float*)(ws + 96468992);   // over Qg (dead after attn)
  u16*   y1b = (u16*)(ws + 113246208);    // over Qg tail / Kg (dead after attn)
  u16*   ff1 = (u16*)(ws + 29360128);     // over cc (dead after Wo GEMM)
  float* ff2 = (float*)(ws + 62914560);   // over cc tail

  // 1) casts / weight transposes to bf16
  cvt_kernel<<<16384, 256, 0, stream>>>(x, xb, 4194304);
  cvt_t_kernel<<<dim3(16, 16, 8), 256, 0, stream>>>(Wq, WqT, 512, 512);
  cvt_t_kernel<<<dim3(16, 16, 8), 256, 0, stream>>>(Wk, WkT, 512, 512);
  cvt_t_kernel<<<dim3(16, 16, 8), 256, 0, stream>>>(Wv, WvT, 512, 512);
  cvt_t_kernel<<<dim3(16, 128, 1), 256, 0, stream>>>(Wo, WoT, 4096, 512);
  cvt_t_kernel<<<dim3(64, 16, 1), 256, 0, stream>>>(W1, W1T, 512, 2048);
  cvt_t_kernel<<<dim3(16, 64, 1), 256, 0, stream>>>(W2, W2T, 2048, 512);

  // 2) per head-group: QKV projections + flash attention -> cc
  dim3 blk(256);
  for (int h0 = 0; h0 < 8; h0 += (int)G) {
    if (G >= 4) {
      dim3 gqkv(4, 64, (unsigned)G);
      gemm_bt<128><<<gqkv, blk, 0, stream>>>(xb, WqT + (size_t)h0 * 262144,
                                             bq + h0 * 512, Qg, 8192, 512, 512,
                                             262144LL, 512LL, (long long)HB, 1);
      gemm_bt<128><<<gqkv, blk, 0, stream>>>(xb, WkT + (size_t)h0 * 262144,
                                             bk + h0 * 512, Kg, 8192, 512, 512,
                                             262144LL, 512LL, (long long)HB, 1);
      gemm_bt<128><<<gqkv, blk, 0, stream>>>(xb, WvT + (size_t)h0 * 262144,
                                             bv + h0 * 512, Vg, 8192, 512, 512,
                                             262144LL, 512LL, (long long)HB, 2);
    } else {
      dim3 gqkv(4, 128, (unsigned)G);
      gemm_bt<64><<<gqkv, blk, 0, stream>>>(xb, WqT + (size_t)h0 * 262144,
                                            bq + h0 * 512, Qg, 8192, 512, 512,
                                            262144LL, 512LL, (long long)HB, 1);
      gemm_bt<64><<<gqkv, blk, 0, stream>>>(xb, WkT + (size_t)h0 * 262144,
                                            bk + h0 * 512, Kg, 8192, 512, 512,
                                            262144LL, 512LL, (long long)HB, 1);
      gemm_bt<64><<<gqkv, blk, 0, stream>>>(xb, WvT + (size_t)h0 * 262144,
                                            bv + h0 * 512, Vg, 8192, 512, 512,
                                            262144LL, 512LL, (long long)HB, 2);
    }
    dim3 gattn(8, 8, (unsigned)G);
    attn_kernel<<<gattn, 512, 0, stream>>>(Qg, Kg, Vg, cc, h0);
  }

  // 3) output projection: mha = concat @ Wo + bo (fp32)
  gemm_bt<64><<<dim3(4, 128, 1), blk, 0, stream>>>(cc, WoT, bo, mha,
                                                   8192, 512, 4096,
                                                   0LL, 0LL, 0LL, 0);

  // 4) y1 = LN(mha + x)
  ln_kernel<<<8192, 256, 0, stream>>>(mha, x, g1, bn1, y1f, y1b, 0);

  // 5) ff1 = y1 @ W1 + b1 (bf16)
  gemm_bt<128><<<dim3(16, 64, 1), blk, 0, stream>>>(y1b, W1T, bf1, ff1,
                                                    8192, 2048, 512,
                                                    0LL, 0LL, 0LL, 1);

  // 6) ff2 = ff1 @ W2 + b2 (fp32)
  gemm_bt<64><<<dim3(4, 128, 1), blk, 0, stream>>>(ff1, W2T, bf2, ff2,
                                                   8192, 512, 2048,
                                                   0LL, 0LL, 0LL, 0);

  // 7) out = LN(relu(ff2) + y1)
  ln_kernel<<<8192, 256, 0, stream>>>(ff2, y1f, g2, bn2, (float*)d_out, nullptr, 1);
}

// Round 4
// 921.073 us; speedup vs baseline: 1.5889x; 1.0317x over previous
//
#include <hip/hip_runtime.h>

using u16 = unsigned short;
using bf16x8 = __attribute__((ext_vector_type(8))) short;
using f32x4 = __attribute__((ext_vector_type(4))) float;

__device__ __forceinline__ u16 f2bf(float f) {
  unsigned x = __float_as_uint(f);
  x += 0x7fffu + ((x >> 16) & 1u);
  return (u16)(x >> 16);
}

// async global->LDS, 16B per lane; lds base must be wave-uniform, each lane's
// 16B lands at lds + lane*16 (m97 pattern).
__device__ __forceinline__ void gl2lds16(const u16* g, u16* l) {
  __builtin_amdgcn_global_load_lds(
      (const __attribute__((address_space(1))) unsigned int*)g,
      (__attribute__((address_space(3))) unsigned int*)l, 16, 0, 0);
}

// ---------------- fp32 -> bf16 conversion ----------------
__global__ __launch_bounds__(256) void cvt_kernel(const float* __restrict__ src,
                                                  u16* __restrict__ dst, int n) {
  int i = blockIdx.x * 256 + threadIdx.x;
  if (i < n) dst[i] = f2bf(src[i]);
}

// ---------------- fp32 [z][K][N] -> bf16 transposed [z][N][K] ----------------
__global__ __launch_bounds__(256) void cvt_t_kernel(
    const float* __restrict__ src, u16* __restrict__ dst, int K, int N) {
  __shared__ float T[32][33];
  int n0 = blockIdx.x * 32, k0 = blockIdx.y * 32;
  const float* s = src + (size_t)blockIdx.z * K * N;
  u16* d = dst + (size_t)blockIdx.z * K * N;
  int tid = threadIdx.x;
  int r = tid >> 3, c4 = (tid & 7) << 2;
  float4 v = *(const float4*)(s + (size_t)(k0 + r) * N + n0 + c4);
  T[r][c4 + 0] = v.x; T[r][c4 + 1] = v.y; T[r][c4 + 2] = v.z; T[r][c4 + 3] = v.w;
  __syncthreads();
  ushort4 o;
  o.x = f2bf(T[c4 + 0][r]); o.y = f2bf(T[c4 + 1][r]);
  o.z = f2bf(T[c4 + 2][r]); o.w = f2bf(T[c4 + 3][r]);
  *(ushort4*)(d + (size_t)(n0 + r) * K + k0 + c4) = o;
}

// ---------------- bf16 GEMM, pre-transposed B, async LDS staging ----------------
// A [M,K] rm bf16, Bt [N,K] rm bf16 (+ per-z offset), bias fp32.
// Tile BM x 128, BK=32; 256 thr = 4 waves (2x2); unpadded LDS stride 32
// (required by global_load_lds wave-contiguous deposit).
// out_mode: 0=fp32 rm, 1=bf16 rm, 2=bf16 V-transpose C[b][col][t], row=b*1024+t.
template<int BM>
__global__ __launch_bounds__(256) void gemm_bt(
    const u16* __restrict__ A, const u16* __restrict__ Bt,
    const float* __restrict__ bias, void* __restrict__ Cout,
    int M, int N, int K, long long sBz, long long sbz, long long sCzBytes,
    int out_mode)
{
  constexpr int MT = BM / 32;
  __shared__ __align__(16) u16 As[BM * 32];
  __shared__ __align__(16) u16 Bs[128 * 32];
  const f32x4 zero4 = {0.f, 0.f, 0.f, 0.f};

  const u16* Bp = Bt + (size_t)blockIdx.z * sBz;
  const float* biasp = bias + (size_t)blockIdx.z * sbz;
  char* Cp = (char*)Cout + (size_t)blockIdx.z * sCzBytes;

  int tid = threadIdx.x;
  int lane = tid & 63, wave = tid >> 6;
  int m = lane & 15, quad = lane >> 4;
  int wm = (wave >> 1) * (BM / 2), wn = (wave & 1) * 64;
  int m0 = blockIdx.y * BM, n0 = blockIdx.x * 128;
  int lr = lane >> 2, lc = (lane & 3) << 3;  // lane's row-offset / col within row

  f32x4 acc[MT][4];
  #pragma unroll
  for (int i = 0; i < MT; i++)
    #pragma unroll
    for (int j = 0; j < 4; j++) acc[i][j] = zero4;

  for (int k0 = 0; k0 < K; k0 += 32) {
    // A tile: each wave-instruction deposits 16 contiguous rows (1 KB)
    #pragma unroll
    for (int i = 0; i < BM / 64; i++) {
      int rb = i * 64 + wave * 16;
      gl2lds16(A + (size_t)(m0 + rb + lr) * K + k0 + lc, &As[rb * 32]);
    }
    // B^T tile: 128 rows
    #pragma unroll
    for (int i = 0; i < 2; i++) {
      int rb = i * 64 + wave * 16;
      gl2lds16(Bp + (size_t)(n0 + rb + lr) * K + k0 + lc, &Bs[rb * 32]);
    }
    __syncthreads();

    bf16x8 af[MT], bfr[4];
    #pragma unroll
    for (int t = 0; t < MT; t++)
      af[t] = *(const bf16x8*)&As[(wm + t * 16 + m) * 32 + quad * 8];
    #pragma unroll
    for (int t = 0; t < 4; t++)
      bfr[t] = *(const bf16x8*)&Bs[(wn + t * 16 + m) * 32 + quad * 8];
    #pragma unroll
    for (int mt = 0; mt < MT; mt++)
      #pragma unroll
      for (int nt = 0; nt < 4; nt++)
        acc[mt][nt] = __builtin_amdgcn_mfma_f32_16x16x32_bf16(af[mt], bfr[nt],
                                                              acc[mt][nt], 0, 0, 0);
    __syncthreads();
  }

  #pragma unroll
  for (int nt = 0; nt < 4; nt++) {
    int col = n0 + wn + nt * 16 + m;
    float bb = biasp[col];
    #pragma unroll
    for (int mt = 0; mt < MT; mt++) {
      #pragma unroll
      for (int r = 0; r < 4; r++) {
        int row = m0 + wm + mt * 16 + quad * 4 + r;
        float v = acc[mt][nt][r] + bb;
        if (out_mode == 1) {
          ((u16*)Cp)[(size_t)row * N + col] = f2bf(v);
        } else if (out_mode == 2) {
          int bb2 = row >> 10, tt2 = row & 1023;
          ((u16*)Cp)[((size_t)bb2 * 512 + col) * 1024 + tt2] = f2bf(v);
        } else {
          ((float*)Cp)[(size_t)row * N + col] = v;
        }
      }
    }
  }
}

// ---------------- flash attention (XCD-swizzled) ----------------
// Q,K: [G][B][1024][512] bf16; V: [G][B][512][1024] bf16 (pre-transposed).
// Out: concat [B][T][H=8][512] bf16. Swizzle: the 8 qb-blocks of one (h,b)
// get flat ids ≡ same (mod 8) -> same XCD under round-robin -> K/V L2 reuse.
__global__ __launch_bounds__(512) void attn_kernel(
    const u16* __restrict__ Qg, const u16* __restrict__ Kg,
    const u16* __restrict__ Vg, u16* __restrict__ Oc, int h0)
{
  __shared__ __align__(16) u16 Kt[32][520];
  __shared__ __align__(16) u16 Vt[256][40];
  __shared__ __align__(16) u16 Pl[8][16][40];
  const f32x4 zero4 = {0.f, 0.f, 0.f, 0.f};

  int F = blockIdx.x + 8 * (blockIdx.y + 8 * blockIdx.z);
  int e = F & 7, g = F >> 3;
  int qb = g & 7;
  int hbl = e + 8 * (g >> 3);      // local head*8 + batch
  int z = hbl >> 3, b = hbl & 7;
  int h = h0 + z;

  size_t hb = ((size_t)z * 8 + b) * (size_t)(1024 * 512);
  const u16* Qp = Qg + hb;
  const u16* Kp = Kg + hb;
  const u16* Vp = Vg + hb;

  int tid = threadIdx.x, lane = tid & 63, wave = tid >> 6;
  int m = lane & 15, quad = lane >> 4;
  int q0 = qb * 128 + wave * 16;

  bf16x8 aq[16];
  #pragma unroll
  for (int kc = 0; kc < 16; kc++)
    aq[kc] = *(const bf16x8*)(Qp + (size_t)(q0 + m) * 512 + kc * 32 + quad * 8);

  f32x4 acc[32];
  #pragma unroll
  for (int dt = 0; dt < 32; dt++) acc[dt] = zero4;
  float mrow[4] = {-1e30f, -1e30f, -1e30f, -1e30f};
  float lrow[4] = {0.f, 0.f, 0.f, 0.f};
  const float scale = 0.04419417382415922f;

  for (int kt = 0; kt < 32; kt++) {
    int kr0 = kt * 32;
    #pragma unroll
    for (int i = 0; i < 4; i++) {
      int gg = tid + 512 * i;
      int r = gg >> 6, c = (gg & 63) << 3;
      *(float4*)&Kt[r][c] = *(const float4*)(Kp + (size_t)(kr0 + r) * 512 + c);
    }
    #pragma unroll
    for (int i = 0; i < 2; i++) {
      int gg = tid + 512 * i;
      int d = gg >> 2, ck = (gg & 3) << 3;
      *(float4*)&Vt[d][ck] = *(const float4*)(Vp + (size_t)d * 1024 + kr0 + ck);
    }
    __syncthreads();

    f32x4 s0 = zero4, s1 = zero4;
    #pragma unroll
    for (int kc = 0; kc < 16; kc++) {
      bf16x8 bk0 = *(const bf16x8*)&Kt[m][kc * 32 + quad * 8];
      bf16x8 bk1 = *(const bf16x8*)&Kt[m + 16][kc * 32 + quad * 8];
      s0 = __builtin_amdgcn_mfma_f32_16x16x32_bf16(aq[kc], bk0, s0, 0, 0, 0);
      s1 = __builtin_amdgcn_mfma_f32_16x16x32_bf16(aq[kc], bk1, s1, 0, 0, 0);
    }

    float al[4];
    #pragma unroll
    for (int r = 0; r < 4; r++) {
      float x0 = s0[r] * scale, x1 = s1[r] * scale;
      float mx = fmaxf(x0, x1);
      #pragma unroll
      for (int off = 1; off < 16; off <<= 1) mx = fmaxf(mx, __shfl_xor(mx, off));
      float mnew = fmaxf(mrow[r], mx);
      float alpha = __expf(mrow[r] - mnew);
      float p0 = __expf(x0 - mnew), p1 = __expf(x1 - mnew);
      float ps = p0 + p1;
      #pragma unroll
      for (int off = 1; off < 16; off <<= 1) ps += __shfl_xor(ps, off);
      lrow[r] = lrow[r] * alpha + ps;
      mrow[r] = mnew;
      al[r] = alpha;
      Pl[wave][quad * 4 + r][m] = f2bf(p0);
      Pl[wave][quad * 4 + r][m + 16] = f2bf(p1);
    }
    asm volatile("s_waitcnt lgkmcnt(0)" ::: "memory");
    bf16x8 ap = *(const bf16x8*)&Pl[wave][m][quad * 8];

    #pragma unroll
    for (int dt = 0; dt < 16; dt++) {
      f32x4 t4 = acc[dt];
      #pragma unroll
      for (int r = 0; r < 4; r++) t4[r] *= al[r];
      bf16x8 bv = *(const bf16x8*)&Vt[dt * 16 + m][quad * 8];
      acc[dt] = __builtin_amdgcn_mfma_f32_16x16x32_bf16(ap, bv, t4, 0, 0, 0);
    }
    __syncthreads();
    #pragma unroll
    for (int i = 0; i < 2; i++) {
      int gg = tid + 512 * i;
      int d = gg >> 2, ck = (gg & 3) << 3;
      *(float4*)&Vt[d][ck] = *(const float4*)(Vp + (size_t)(256 + d) * 1024 + kr0 + ck);
    }
    __syncthreads();
    #pragma unroll
    for (int dt = 0; dt < 16; dt++) {
      f32x4 t4 = acc[16 + dt];
      #pragma unroll
      for (int r = 0; r < 4; r++) t4[r] *= al[r];
      bf16x8 bv = *(const bf16x8*)&Vt[dt * 16 + m][quad * 8];
      acc[16 + dt] = __builtin_amdgcn_mfma_f32_16x16x32_bf16(ap, bv, t4, 0, 0, 0);
    }
    __syncthreads();
  }

  float linv[4];
  #pragma unroll
  for (int r = 0; r < 4; r++) linv[r] = 1.f / lrow[r];
  #pragma unroll
  for (int dt = 0; dt < 32; dt++) {
    #pragma unroll
    for (int r = 0; r < 4; r++) {
      size_t trow = (size_t)b * 1024 + q0 + quad * 4 + r;
      Oc[(trow * 8 + h) * 512 + dt * 16 + m] = f2bf(acc[dt][r] * linv[r]);
    }
  }
}

// ---------------- fused residual + LayerNorm ----------------
__global__ __launch_bounds__(256) void ln_kernel(
    const float* __restrict__ xin, const float* __restrict__ res,
    const float* __restrict__ gam, const float* __restrict__ bet,
    float* __restrict__ outf, u16* __restrict__ outb, int do_relu)
{
  __shared__ float red[4];
  __shared__ float red2[4];
  int row = blockIdx.x, t = threadIdx.x;
  size_t base = (size_t)row * 512;
  float a0 = xin[base + t], a1 = xin[base + 256 + t];
  if (do_relu) { a0 = fmaxf(a0, 0.f); a1 = fmaxf(a1, 0.f); }
  a0 += res[base + t]; a1 += res[base + 256 + t];

  float s = a0 + a1;
  #pragma unroll
  for (int off = 32; off > 0; off >>= 1) s += __shfl_xor(s, off);
  if ((t & 63) == 0) red[t >> 6] = s;
  __syncthreads();
  float mu = (red[0] + red[1] + red[2] + red[3]) * (1.f / 512.f);

  float d0 = a0 - mu, d1 = a1 - mu;
  float q = d0 * d0 + d1 * d1;
  #pragma unroll
  for (int off = 32; off > 0; off >>= 1) q += __shfl_xor(q, off);
  if ((t & 63) == 0) red2[t >> 6] = q;
  __syncthreads();
  float var = (red2[0] + red2[1] + red2[2] + red2[3]) * (1.f / 512.f);
  float rs = rsqrtf(var + 1e-5f);

  float o0 = d0 * rs * gam[t] + bet[t];
  float o1 = d1 * rs * gam[t + 256] + bet[t + 256];
  outf[base + t] = o0;
  outf[base + 256 + t] = o1;
  if (outb) { outb[base + t] = f2bf(o0); outb[base + 256 + t] = f2bf(o1); }
}

// ---------------- host launch ----------------
extern "C" void kernel_launch(void* const* d_in, const int* in_sizes, int n_in,
                              void* d_out, int out_size, void* d_ws, size_t ws_size,
                              hipStream_t stream) {
  const float* x   = (const float*)d_in[0];
  const float* Wq  = (const float*)d_in[1];
  const float* bq  = (const float*)d_in[2];
  const float* Wk  = (const float*)d_in[3];
  const float* bk  = (const float*)d_in[4];
  const float* Wv  = (const float*)d_in[5];
  const float* bv  = (const float*)d_in[6];
  const float* Wo  = (const float*)d_in[7];
  const float* bo  = (const float*)d_in[8];
  const float* g1  = (const float*)d_in[9];
  const float* bn1 = (const float*)d_in[10];
  const float* W1  = (const float*)d_in[11];
  const float* bf1 = (const float*)d_in[12];
  const float* W2  = (const float*)d_in[13];
  const float* bf2 = (const float*)d_in[14];
  const float* g2  = (const float*)d_in[15];
  const float* bn2 = (const float*)d_in[16];

  const size_t HB = 8388608;  // bytes per head per tensor
  size_t G = 1;
  if (ws_size >= 113246208ULL + 25165824ULL * 8) G = 8;
  else if (ws_size >= 113246208ULL + 25165824ULL * 4) G = 4;
  else if (ws_size >= 113246208ULL + 25165824ULL * 2) G = 2;

  char* ws = (char*)d_ws;
  u16* xb  = (u16*)(ws + 0);
  u16* WqT = (u16*)(ws + 8388608);
  u16* WkT = (u16*)(ws + 12582912);
  u16* WvT = (u16*)(ws + 16777216);
  u16* WoT = (u16*)(ws + 20971520);
  u16* W1T = (u16*)(ws + 25165824);
  u16* W2T = (u16*)(ws + 27262976);
  u16* cc  = (u16*)(ws + 29360128);
  u16* Qg  = (u16*)(ws + 96468992);
  u16* Kg  = (u16*)(ws + 96468992 + G * HB);
  u16* Vg  = (u16*)(ws + 96468992 + 2 * G * HB);
  float* mha = (float*)(ws + 96468992 + 3 * G * HB);
  float* y1f = (float*)(ws + 96468992);
  u16*   y1b = (u16*)(ws + 113246208);
  u16*   ff1 = (u16*)(ws + 29360128);
  float* ff2 = (float*)(ws + 62914560);

  cvt_kernel<<<16384, 256, 0, stream>>>(x, xb, 4194304);
  cvt_t_kernel<<<dim3(16, 16, 8), 256, 0, stream>>>(Wq, WqT, 512, 512);
  cvt_t_kernel<<<dim3(16, 16, 8), 256, 0, stream>>>(Wk, WkT, 512, 512);
  cvt_t_kernel<<<dim3(16, 16, 8), 256, 0, stream>>>(Wv, WvT, 512, 512);
  cvt_t_kernel<<<dim3(16, 128, 1), 256, 0, stream>>>(Wo, WoT, 4096, 512);
  cvt_t_kernel<<<dim3(64, 16, 1), 256, 0, stream>>>(W1, W1T, 512, 2048);
  cvt_t_kernel<<<dim3(16, 64, 1), 256, 0, stream>>>(W2, W2T, 2048, 512);

  dim3 blk(256);
  for (int h0 = 0; h0 < 8; h0 += (int)G) {
    if (G >= 4) {
      dim3 gqkv(4, 64, (unsigned)G);
      gemm_bt<128><<<gqkv, blk, 0, stream>>>(xb, WqT + (size_t)h0 * 262144,
                                             bq + h0 * 512, Qg, 8192, 512, 512,
                                             262144LL, 512LL, (long long)HB, 1);
      gemm_bt<128><<<gqkv, blk, 0, stream>>>(xb, WkT + (size_t)h0 * 262144,
                                             bk + h0 * 512, Kg, 8192, 512, 512,
                                             262144LL, 512LL, (long long)HB, 1);
      gemm_bt<128><<<gqkv, blk, 0, stream>>>(xb, WvT + (size_t)h0 * 262144,
                                             bv + h0 * 512, Vg, 8192, 512, 512,
                                             262144LL, 512LL, (long long)HB, 2);
    } else {
      dim3 gqkv(4, 128, (unsigned)G);
      gemm_bt<64><<<gqkv, blk, 0, stream>>>(xb, WqT + (size_t)h0 * 262144,
                                            bq + h0 * 512, Qg, 8192, 512, 512,
                                            262144LL, 512LL, (long long)HB, 1);
      gemm_bt<64><<<gqkv, blk, 0, stream>>>(xb, WkT + (size_t)h0 * 262144,
                                            bk + h0 * 512, Kg, 8192, 512, 512,
                                            262144LL, 512LL, (long long)HB, 1);
      gemm_bt<64><<<gqkv, blk, 0, stream>>>(xb, WvT + (size_t)h0 * 262144,
                                            bv + h0 * 512, Vg, 8192, 512, 512,
                                            262144LL, 512LL, (long long)HB, 2);
    }
    dim3 gattn(8, 8, (unsigned)G);
    attn_kernel<<<gattn, 512, 0, stream>>>(Qg, Kg, Vg, cc, h0);
  }

  gemm_bt<64><<<dim3(4, 128, 1), blk, 0, stream>>>(cc, WoT, bo, mha,
                                                   8192, 512, 4096,
                                                   0LL, 0LL, 0LL, 0);
  ln_kernel<<<8192, 256, 0, stream>>>(mha, x, g1, bn1, y1f, y1b, 0);
  gemm_bt<128><<<dim3(16, 64, 1), blk, 0, stream>>>(y1b, W1T, bf1, ff1,
                                                    8192, 2048, 512,
                                                    0LL, 0LL, 0LL, 1);
  gemm_bt<64><<<dim3(4, 128, 1), blk, 0, stream>>>(ff1, W2T, bf2, ff2,
                                                   8192, 512, 2048,
                                                   0LL, 0LL, 0LL, 0);
  ln_kernel<<<8192, 256, 0, stream>>>(ff2, y1f, g2, bn2, (float*)d_out, nullptr, 1);
}